// Round 4
// baseline (594.576 us; speedup 1.0000x reference)
//
#include <hip/hip_runtime.h>
#include <math.h>
#include <utility>

#define NLEADS 61
#define AIL __attribute__((always_inline))

typedef float f2 __attribute__((ext_vector_type(2)));

// Guaranteed-unroll helper: indices are compile-time constants -> SROA to regs.
template <int... Is, typename F>
__device__ __forceinline__ void sf_(std::integer_sequence<int, Is...>, F&& f) {
    (f(std::integral_constant<int, Is>{}), ...);
}
template <int N, typename F>
__device__ __forceinline__ void static_for(F&& f) {
    sf_(std::make_integer_sequence<int, N>{}, (F&&)f);
}

__device__ __forceinline__ float4 ld4(const float* p) { return *(const float4*)p; }
__device__ __forceinline__ float2 ld2(const float* p) { return *(const float2*)p; }
__device__ __forceinline__ f2 sp(float x) { return f2{x, x}; }          // splat
__device__ __forceinline__ f2 pfma(f2 a, f2 b, f2 c) {                  // v_pk_fma_f32
    return __builtin_elementwise_fma(a, b, c);
}
__device__ __forceinline__ f2 pmax(f2 a, f2 b) {                        // v_pk_max_f32
    return __builtin_elementwise_max(a, b);
}

template <int C> __device__ __forceinline__ float f4c(float4 v) {
    if constexpr (C == 0) return v.x;
    else if constexpr (C == 1) return v.y;
    else if constexpr (C == 2) return v.z;
    else return v.w;
}
template <int C> __device__ __forceinline__ float f6(float4 a, float2 b) {
    if constexpr (C < 4) return f4c<C>(a);
    else if constexpr (C == 4) return b.x;
    else return b.y;
}
template <int K> __device__ __forceinline__ float w12(float4 w0, float4 w1, float4 w2) {
    if constexpr (K < 4) return f4c<K>(w0);
    else if constexpr (K < 8) return f4c<K - 4>(w1);
    else return f4c<K - 8>(w2);
}

// LDS (floats): A[0..8703]  : h1p[8][16][68] (col-padded: col c at idx c+1)
//                             after conv2: sh3@0[256], spart@256[256], shf@512[64],
//                             slog@580[3], sfc@600[195]
//               H2[..1288]  : h2p[16][4][20] (col-padded) + 8 guard
//               ZR [68]     : shared zero row (OOB row reads for conv2/conv3)
// Total 10060 floats = 40240 B -> 40448 B LDS block, 4 blocks/CU (16 waves).
// conv1/conv2 use v_pk_fma_f32 over oc-PAIRS: acc component i = output oc+i,
// weight operand = uniform pair {w_oc, w_oc+1}, input = splat {x,x}. Each
// component's accumulation order (ic,kh,kw) and fma semantics are unchanged
// -> bit-exact vs the scalar version (scalar fp32 FMA is half-rate on CDNA;
// packed is the advertised-157TF path).
__global__ __launch_bounds__(256, 4)
void lead_cnn_kernel(const float* __restrict__ x,
                     const float* __restrict__ w1g, const float* __restrict__ b1g,
                     const float* __restrict__ w2g, const float* __restrict__ b2g,
                     const float* __restrict__ w3g, const float* __restrict__ b3g,
                     const float* __restrict__ w4g, const float* __restrict__ b4g,
                     const float* __restrict__ fcwg, const float* __restrict__ fcbg,
                     float* __restrict__ preds)
{
    __shared__ __align__(16) float smem[10060];
    float* const A  = smem;
    float* const H2 = smem + 8704;
    float* const ZR = smem + 9992;

    const int t = threadIdx.x;
    const int b = blockIdx.x;
    const int l = blockIdx.y;

    const float* xg  = x + ((size_t)b * NLEADS + l) * 8000;
    const float* w1l = w1g + l * 96;       // wave-uniform -> s_load
    const float* b1l = b1g + l * 8;

    // ---- LDS pad init (zero row + col pads), independent of conv1 compute ----
    if (t < 68) ZR[t] = 0.f;
    for (int i = t; i < 640; i += 256) {          // h1p cols 0 and 64..67
        const int ch = i / 80, j = i - ch * 80;
        const int r = j / 5, k = j - r * 5;
        A[ch * 1088 + r * 68 + ((k == 0) ? 0 : (63 + k))] = 0.f;
    }
    for (int i = t; i < 128; i += 256) {          // h2p col pads 0 and 17
        const int ch = i >> 3, r = (i >> 1) & 3;
        H2[ch * 80 + r * 20 + ((i & 1) ? 17 : 0)] = 0.f;
    }

    // ===== conv1 (8,1,3,4) s(1,2) p(1,2) + pool2 + relu ============================
    // Vertical pairing: each item = (php, pw) computes pooled rows {2php, 2php+1}
    // from 6 input rows (4php-1 .. 4php+4). 504 items over 2 half-iterations;
    // BOTH halves' global loads are issued before any compute (one latency wait).
    const int item0 = t;                     // 0..255  -> php 0..4, always valid
    const int item1 = t + 256;               // 256..511 -> valid iff < 504
    const int php0 = item0 / 63, pw0 = item0 - php0 * 63;
    int       php1 = item1 / 63;
    const int pw1  = item1 - php1 * 63;
    const bool valid1 = (item1 < 504);
    php1 = valid1 ? php1 : 7;                // clamp for address safety

    float xwA[36], xwB[36];                  // [lr*6 + c], lr = input row 4php-1+lr

    auto ldx = [&](float (&xw)[36], const int php, const int pw) AIL {
        const int c1 = (pw == 0) ? 0 : (4 * pw - 2);      // 8B-aligned
        const int c3 = (pw >= 62) ? 248 : (4 * pw + 2);   // 8B-aligned, in-bounds
        const bool lok = (pw > 0), rok = (pw < 62);
        {   // lr = 0 : input row 4php-1, OOB only when php==0
            const bool ok = (php > 0);
            const float* xr = xg + (ok ? (4 * php - 1) : 0) * 250;
            const float2 e0 = ld2(xr + c1);
            const float2 e1 = ld2(xr + 4 * pw);
            const float2 e2 = ld2(xr + c3);
            const bool okl = ok & lok, okr = ok & rok;
            xw[0] = okl ? e0.x : 0.f;  xw[1] = okl ? e0.y : 0.f;
            xw[2] = ok  ? e1.x : 0.f;  xw[3] = ok  ? e1.y : 0.f;
            xw[4] = okr ? e2.x : 0.f;  xw[5] = okr ? e2.y : 0.f;
        }
        static_for<4>([&](auto RR) AIL {     // lr = 1..4 : rows 4php..4php+3, in range
            constexpr int lr = RR.value + 1;
            const float* xr = xg + (4 * php - 1 + lr) * 250;
            const float2 e0 = ld2(xr + c1);
            const float2 e1 = ld2(xr + 4 * pw);
            const float2 e2 = ld2(xr + c3);
            xw[lr*6+0] = lok ? e0.x : 0.f;  xw[lr*6+1] = lok ? e0.y : 0.f;
            xw[lr*6+2] = e1.x;              xw[lr*6+3] = e1.y;
            xw[lr*6+4] = rok ? e2.x : 0.f;  xw[lr*6+5] = rok ? e2.y : 0.f;
        });
        {   // lr = 5 : input row 4php+4, OOB only when php==7
            const bool ok = (php < 7);
            const float* xr = xg + (ok ? (4 * php + 4) : 31) * 250;
            const float2 e0 = ld2(xr + c1);
            const float2 e1 = ld2(xr + 4 * pw);
            const float2 e2 = ld2(xr + c3);
            const bool okl = ok & lok, okr = ok & rok;
            xw[30] = okl ? e0.x : 0.f;  xw[31] = okl ? e0.y : 0.f;
            xw[32] = ok  ? e1.x : 0.f;  xw[33] = ok  ? e1.y : 0.f;
            xw[34] = okr ? e2.x : 0.f;  xw[35] = okr ? e2.y : 0.f;
        }
    };

    ldx(xwA, php0, pw0);     // issue all 36 loads ...
    ldx(xwB, php1, pw1);     // ... for both halves before first use

    auto cmp1 = [&](const float (&xw)[36], const int php, const int pw,
                    const bool dostore) AIL {
        const int sb = (2 * php) * 68 + pw + 1;          // col c -> idx c+1
        static_for<4>([&](auto OCP) AIL {                // oc pair {2p, 2p+1}
            constexpr int oc0 = 2 * OCP.value;
            constexpr int oc1 = oc0 + 1;
            f2 p2[8];                                     // [conv_row j][dc], {oc0,oc1}
            static_for<8>([&](auto I) AIL { p2[I.value] = f2{0.f, 0.f}; });
            static_for<3>([&](auto KH) AIL {
                constexpr int kh = KH.value;
                static_for<4>([&](auto KW) AIL {
                    constexpr int kw = KW.value;
                    const f2 wv2 = f2{ w1l[oc0 * 12 + kh * 4 + kw],
                                       w1l[oc1 * 12 + kh * 4 + kw] };  // uniform pair
                    static_for<4>([&](auto J) AIL {       // conv rows 4php+j
                        constexpr int j = J.value;
                        p2[j*2+0] = pfma(wv2, sp(xw[(j + kh) * 6 + kw]),     p2[j*2+0]);
                        p2[j*2+1] = pfma(wv2, sp(xw[(j + kh) * 6 + kw + 2]), p2[j*2+1]);
                    });
                });
            });
            // pool rows {j=0,1} -> out row 2php ; {j=2,3} -> out row 2php+1
            const f2 m0 = pmax(pmax(p2[0], p2[1]), pmax(p2[2], p2[3]));
            const f2 m1 = pmax(pmax(p2[4], p2[5]), pmax(p2[6], p2[7]));
            const f2 bb = f2{ b1l[oc0], b1l[oc1] };
            const f2 z  = f2{0.f, 0.f};
            const f2 v0 = pmax(m0 + bb, z);
            const f2 v1 = pmax(m1 + bb, z);
            if (dostore) {
                A[oc0 * 1088 + sb]      = v0.x;
                A[oc0 * 1088 + sb + 68] = v1.x;
                A[oc1 * 1088 + sb]      = v0.y;
                A[oc1 * 1088 + sb + 68] = v1.y;
            }
        });
    };
    cmp1(xwA, php0, pw0, true);
    cmp1(xwB, php1, pw1, valid1);
    __syncthreads();

    // ===== conv2 (16,8,4,3) s(2,2) p(1,1) + pool2 + relu -> h2p (16,4,16) ==========
    // 2-deep software pipeline over ic (named double buffers) + oc-pair packing.
    {
        const int s2 = t & 63;
        const int ogu = __builtin_amdgcn_readfirstlane(t >> 6);   // wave-uniform
        const int ph2 = s2 >> 4, pw2 = s2 & 15;
        struct Buf2 { float4 ya[6]; float2 yb[6]; };
        Buf2 bA, bB;
        const float* const Pz = ZR + 4 * pw2;
        const float* const Pm = A + (4 * ph2 - 1) * 68 + 4 * pw2; // row r: +r*68+ic*1088

        auto ldic = [&](auto ICC, Buf2& bb) AIL {
            constexpr int ic = ICC.value;
            {   // r=0: OOB only when ph2==0 -> zero row
                const float* hp = (ph2 > 0) ? (Pm + ic * 1088) : Pz;
                bb.ya[0] = ld4(hp); bb.yb[0] = ld2(hp + 4);
            }
            static_for<4>([&](auto RR) AIL {   // r=1..4 always in-range -> imm offsets
                constexpr int r = RR.value + 1;
                const float* hp = Pm + ic * 1088 + r * 68;
                bb.ya[r] = ld4(hp); bb.yb[r] = ld2(hp + 4);
            });
            {   // r=5: OOB only when ph2==3 -> zero row
                const float* hp = (ph2 < 3) ? (Pm + ic * 1088 + 5 * 68) : Pz;
                bb.ya[5] = ld4(hp); bb.yb[5] = ld2(hp + 4);
            }
        };

        f2 a2p[2][4];                          // [olp][spatial], {oc=2olp, oc=2olp+1}
        static_for<2>([&](auto P) AIL {
            static_for<4>([&](auto S) AIL { a2p[P.value][S.value] = f2{0.f, 0.f}; });
        });

        auto cmpic = [&](auto ICC, const Buf2& bb) AIL {
            constexpr int ic = ICC.value;
            static_for<2>([&](auto OLP) AIL {
                constexpr int olp = OLP.value;
                const float* wp0 = w2g + ((size_t)((l * 16 + ogu * 4 + 2*olp    ) * 8 + ic)) * 12;
                const float* wp1 = w2g + ((size_t)((l * 16 + ogu * 4 + 2*olp + 1) * 8 + ic)) * 12;
                static_for<4>([&](auto KH) AIL {
                    constexpr int kh = KH.value;
                    static_for<3>([&](auto KW) AIL {
                        constexpr int kw = KW.value;
                        const f2 wv2 = f2{ wp0[kh * 3 + kw], wp1[kh * 3 + kw] };  // uniform
                        a2p[olp][0] = pfma(wv2, sp(f6<kw    >(bb.ya[kh],     bb.yb[kh]    )), a2p[olp][0]);
                        a2p[olp][1] = pfma(wv2, sp(f6<kw + 2>(bb.ya[kh],     bb.yb[kh]    )), a2p[olp][1]);
                        a2p[olp][2] = pfma(wv2, sp(f6<kw    >(bb.ya[kh + 2], bb.yb[kh + 2])), a2p[olp][2]);
                        a2p[olp][3] = pfma(wv2, sp(f6<kw + 2>(bb.ya[kh + 2], bb.yb[kh + 2])), a2p[olp][3]);
                    });
                });
            });
        };

        ldic(std::integral_constant<int, 0>{}, bA);
        static_for<8>([&](auto IC) AIL {
            constexpr int ic = IC.value;
            if constexpr (ic < 7) {
                if constexpr ((ic + 1) & 1) ldic(std::integral_constant<int, ic + 1>{}, bB);
                else                        ldic(std::integral_constant<int, ic + 1>{}, bA);
            }
            if constexpr (ic & 1) cmpic(IC, bB);
            else                  cmpic(IC, bA);
        });

        static_for<2>([&](auto OLP) AIL {
            constexpr int olp = OLP.value;
            const int oc0 = ogu * 4 + 2 * olp, oc1 = oc0 + 1;
            const f2 m = pmax(pmax(a2p[olp][0], a2p[olp][1]),
                              pmax(a2p[olp][2], a2p[olp][3]));
            const f2 bb2 = f2{ b2g[l * 16 + oc0], b2g[l * 16 + oc1] };
            const f2 v = pmax(m + bb2, f2{0.f, 0.f});
            H2[oc0 * 80 + ph2 * 20 + pw2 + 1] = v.x;
            H2[oc1 * 80 + ph2 * 20 + pw2 + 1] = v.y;
        });
    }
    __syncthreads();

    // ===== conv3 (32,16,3,4) s(1,2) p(1,1) + pool2 + relu -> sh3 (32,2,4) ==========
    // Same 2-deep pipeline; also prefetches the per-lane global weight loads.
    {
        const int oc3 = t >> 3, s3 = t & 7;
        const int ph3 = s3 >> 2, pw3 = s3 & 3;
        const float* w3l = w3g + (size_t)l * 6144 + oc3 * 192;
        const float b3v = b3g[l * 32 + oc3];
        struct Buf3 { float4 za[4]; float2 zb[4]; float4 q0, q1, q2; };
        Buf3 cA, cB;
        const float* const Pz = ZR + 4 * pw3;
        const float* const Pm = H2 + (2 * ph3 - 1) * 20 + 4 * pw3; // row r: +r*20+ic*80

        auto ldic3 = [&](auto ICC, Buf3& bb) AIL {
            constexpr int ic = ICC.value;
            {   // r=0: OOB only when ph3==0
                const float* zp = (ph3 > 0) ? (Pm + ic * 80) : Pz;
                bb.za[0] = ld4(zp); bb.zb[0] = ld2(zp + 4);
            }
            static_for<2>([&](auto RR) AIL {   // r=1,2 always in-range
                constexpr int r = RR.value + 1;
                const float* zp = Pm + ic * 80 + r * 20;
                bb.za[r] = ld4(zp); bb.zb[r] = ld2(zp + 4);
            });
            {   // r=3: OOB only when ph3==1
                const float* zp = (ph3 < 1) ? (Pm + ic * 80 + 3 * 20) : Pz;
                bb.za[3] = ld4(zp); bb.zb[3] = ld2(zp + 4);
            }
            bb.q0 = ld4(w3l + ic * 12);
            bb.q1 = ld4(w3l + ic * 12 + 4);
            bb.q2 = ld4(w3l + ic * 12 + 8);
        };

        float a30 = 0.f, a31 = 0.f, a32 = 0.f, a33 = 0.f;
        auto cmpic3 = [&](const Buf3& bb) AIL {
            static_for<3>([&](auto KH) AIL {
                constexpr int kh = KH.value;
                static_for<4>([&](auto KW) AIL {
                    constexpr int kw = KW.value;
                    const float wv = w12<kh * 4 + kw>(bb.q0, bb.q1, bb.q2);
                    a30 = fmaf(wv, f6<kw>(bb.za[kh], bb.zb[kh]), a30);
                    a31 = fmaf(wv, f6<kw + 2>(bb.za[kh], bb.zb[kh]), a31);
                    a32 = fmaf(wv, f6<kw>(bb.za[kh + 1], bb.zb[kh + 1]), a32);
                    a33 = fmaf(wv, f6<kw + 2>(bb.za[kh + 1], bb.zb[kh + 1]), a33);
                });
            });
        };

        ldic3(std::integral_constant<int, 0>{}, cA);
        static_for<16>([&](auto IC) AIL {
            constexpr int ic = IC.value;
            if constexpr (ic < 15) {
                if constexpr ((ic + 1) & 1) ldic3(std::integral_constant<int, ic + 1>{}, cB);
                else                        ldic3(std::integral_constant<int, ic + 1>{}, cA);
            }
            if constexpr (ic & 1) cmpic3(cB);
            else                  cmpic3(cA);
        });

        const float m = fmaxf(fmaxf(a30, a31), fmaxf(a32, a33));
        A[oc3 * 8 + s3] = fmaxf(m + b3v, 0.f);    // sh3, h1p region is dead
    }
    __syncthreads();

    // ===== conv4 (64,32,2,4) VALID -> (64,) + fc-weight staging ====================
    {
        if (t < 192) A[600 + t] = fcwg[l * 192 + t];
        else if (t < 195) A[600 + t] = fcbg[l * 3 + (t - 192)];

        const int oc4 = t >> 2, part = t & 3;
        const float* w4p = w4g + (size_t)l * 16384 + oc4 * 256 + part * 64;
        float s4 = 0.f;
        static_for<8>([&](auto J) AIL {
            constexpr int j = J.value;
            const float4 wa = ld4(w4p + j * 8);
            const float4 wb = ld4(w4p + j * 8 + 4);
            const float* xx = A + (part * 8 + j) * 8;
            const float4 xA = ld4(xx), xB = ld4(xx + 4);
            s4 = fmaf(wa.x, xA.x, s4); s4 = fmaf(wa.y, xA.y, s4);
            s4 = fmaf(wa.z, xA.z, s4); s4 = fmaf(wa.w, xA.w, s4);
            s4 = fmaf(wb.x, xB.x, s4); s4 = fmaf(wb.y, xB.y, s4);
            s4 = fmaf(wb.z, xB.z, s4); s4 = fmaf(wb.w, xB.w, s4);
        });
        A[256 + part * 64 + oc4] = s4;            // spart
    }
    __syncthreads();
    if (t < 64)
        A[512 + t] = A[256 + t] + A[320 + t] + A[384 + t] + A[448 + t]
                   + b4g[l * 64 + t];             // shf
    __syncthreads();

    // ===== FC (3x64) + softmax =====================================================
    if (t < 3) {
        float s = A[792 + t];                     // fcb
        static_for<64>([&](auto I) AIL {
            s = fmaf(A[600 + t * 64 + I.value], A[512 + I.value], s);
        });
        A[580 + t] = s;                           // slog
    }
    __syncthreads();
    if (t == 0) {
        const float a0 = A[580], a1 = A[581], a2 = A[582];
        const float m = fmaxf(a0, fmaxf(a1, a2));
        const float e0 = expf(a0 - m), e1 = expf(a1 - m), e2 = expf(a2 - m);
        const float inv = 1.f / (e0 + e1 + e2);
        float* pr = preds + ((size_t)b * NLEADS + l) * 3;
        pr[0] = e0 * inv; pr[1] = e1 * inv; pr[2] = e2 * inv;
    }
}

// Cross-lead multiplicative fusion loss. One thread per (b, class).
__global__ void fusion_loss_kernel(const float* __restrict__ preds,
                                   float* __restrict__ out, int B)
{
    const int idx = blockIdx.x * blockDim.x + threadIdx.x;
    if (idx >= B * 3) return;
    const int b = idx / 3;
    const int c = idx - 3 * b;
    const float* p = preds + (size_t)b * (NLEADS * 3) + c;
    float S = 0.f;                                // log prod(1-pj)
    for (int j = 0; j < NLEADS; ++j) S += logf(1.f - p[j * 3]);
    const float be = 2.0f / 60.0f;
    float loss = 0.f;
    for (int j = 0; j < NLEADS; ++j) {
        const float pj = p[j * 3];
        loss += expf(be * (S - logf(1.f - pj))) * logf(pj);
    }
    out[idx] = -loss;
}

extern "C" void kernel_launch(void* const* d_in, const int* in_sizes, int n_in,
                              void* d_out, int out_size, void* d_ws, size_t ws_size,
                              hipStream_t stream)
{
    const float* x   = (const float*)d_in[0];
    const float* w1  = (const float*)d_in[1];
    const float* b1  = (const float*)d_in[2];
    const float* w2  = (const float*)d_in[3];
    const float* b2  = (const float*)d_in[4];
    const float* w3  = (const float*)d_in[5];
    const float* b3  = (const float*)d_in[6];
    const float* w4  = (const float*)d_in[7];
    const float* b4  = (const float*)d_in[8];
    const float* fcw = (const float*)d_in[9];
    const float* fcb = (const float*)d_in[10];

    const int B = in_sizes[0] / (NLEADS * 32 * 250);   // 128
    float* preds = (float*)d_ws;                        // B*61*3 floats

    dim3 grid(B, NLEADS);
    hipLaunchKernelGGL(lead_cnn_kernel, grid, dim3(256), 0, stream,
                       x, w1, b1, w2, b2, w3, b3, w4, b4, fcw, fcb, preds);

    const int total = B * 3;
    hipLaunchKernelGGL(fusion_loss_kernel, dim3((total + 255) / 256), dim3(256),
                       0, stream, preds, (float*)d_out, B);
}

// Round 5
// 512.201 us; speedup vs baseline: 1.1608x; 1.1608x over previous
//
#include <hip/hip_runtime.h>
#include <math.h>
#include <utility>

#define NLEADS 61
#define AIL __attribute__((always_inline))

// Guaranteed-unroll helper: indices are compile-time constants -> SROA to regs.
template <int... Is, typename F>
__device__ __forceinline__ void sf_(std::integer_sequence<int, Is...>, F&& f) {
    (f(std::integral_constant<int, Is>{}), ...);
}
template <int N, typename F>
__device__ __forceinline__ void static_for(F&& f) {
    sf_(std::make_integer_sequence<int, N>{}, (F&&)f);
}

__device__ __forceinline__ float4 ld4(const float* p) { return *(const float4*)p; }
__device__ __forceinline__ float2 ld2(const float* p) { return *(const float2*)p; }

template <int C> __device__ __forceinline__ float f4c(float4 v) {
    if constexpr (C == 0) return v.x;
    else if constexpr (C == 1) return v.y;
    else if constexpr (C == 2) return v.z;
    else return v.w;
}
template <int C> __device__ __forceinline__ float f6(float4 a, float2 b) {
    if constexpr (C < 4) return f4c<C>(a);
    else if constexpr (C == 4) return b.x;
    else return b.y;
}
template <int K> __device__ __forceinline__ float w12(float4 w0, float4 w1, float4 w2) {
    if constexpr (K < 4) return f4c<K>(w0);
    else if constexpr (K < 8) return f4c<K - 4>(w1);
    else return f4c<K - 8>(w2);
}

// LDS (floats): A[0..8703]  : h1p[8][16][68] (col-padded: col c at idx c+1)
//                             after conv2: sh3@0[256], spart@256[256], shf@512[64],
//                             slog@580[3], sfc@600[195]
//               H2[..1288]  : h2p[16][4][20] (col-padded) + 8 guard
//               ZR [68]     : shared zero row (OOB row reads for conv2/conv3)
// Total 10060 floats = 40240 B -> 40448 B LDS block, 4 blocks/CU (16 waves).
// Scalar v_fma_f32 is the full-rate fp32 path on CDNA4 (157.3 TF = 32768
// lanes x 2 flop x 2.4 GHz); do NOT pack (R4 postmortem: f2 packing spilled).
__global__ __launch_bounds__(256, 4)
void lead_cnn_kernel(const float* __restrict__ x,
                     const float* __restrict__ w1g, const float* __restrict__ b1g,
                     const float* __restrict__ w2g, const float* __restrict__ b2g,
                     const float* __restrict__ w3g, const float* __restrict__ b3g,
                     const float* __restrict__ w4g, const float* __restrict__ b4g,
                     const float* __restrict__ fcwg, const float* __restrict__ fcbg,
                     float* __restrict__ preds)
{
    __shared__ __align__(16) float smem[10060];
    float* const A  = smem;
    float* const H2 = smem + 8704;
    float* const ZR = smem + 9992;

    const int t = threadIdx.x;
    const int b = blockIdx.x;
    const int l = blockIdx.y;

    const float* xg  = x + ((size_t)b * NLEADS + l) * 8000;
    const float* w1l = w1g + l * 96;       // wave-uniform -> s_load
    const float* b1l = b1g + l * 8;

    // ===== conv1 (8,1,3,4) s(1,2) p(1,2) + pool2 + relu ============================
    // Vertical pairing: each item = (php, pw) computes pooled rows {2php, 2php+1}
    // from 6 input rows (4php-1 .. 4php+4). 504 items over 2 half-iterations;
    // BOTH halves' global loads are issued FIRST (before the LDS pad-init) so the
    // HBM latency hides under the init stores.
    const int item0 = t;                     // 0..255  -> php 0..4, always valid
    const int item1 = t + 256;               // 256..511 -> valid iff < 504
    const int php0 = item0 / 63, pw0 = item0 - php0 * 63;
    int       php1 = item1 / 63;
    const int pw1  = item1 - php1 * 63;
    const bool valid1 = (item1 < 504);
    php1 = valid1 ? php1 : 7;                // clamp for address safety

    float xwA[36], xwB[36];                  // [lr*6 + c], lr = input row 4php-1+lr

    auto ldx = [&](float (&xw)[36], const int php, const int pw) AIL {
        const int c1 = (pw == 0) ? 0 : (4 * pw - 2);      // 8B-aligned
        const int c3 = (pw >= 62) ? 248 : (4 * pw + 2);   // 8B-aligned, in-bounds
        const bool lok = (pw > 0), rok = (pw < 62);
        {   // lr = 0 : input row 4php-1, OOB only when php==0
            const bool ok = (php > 0);
            const float* xr = xg + (ok ? (4 * php - 1) : 0) * 250;
            const float2 e0 = ld2(xr + c1);
            const float2 e1 = ld2(xr + 4 * pw);
            const float2 e2 = ld2(xr + c3);
            const bool okl = ok & lok, okr = ok & rok;
            xw[0] = okl ? e0.x : 0.f;  xw[1] = okl ? e0.y : 0.f;
            xw[2] = ok  ? e1.x : 0.f;  xw[3] = ok  ? e1.y : 0.f;
            xw[4] = okr ? e2.x : 0.f;  xw[5] = okr ? e2.y : 0.f;
        }
        static_for<4>([&](auto RR) AIL {     // lr = 1..4 : rows 4php..4php+3, in range
            constexpr int lr = RR.value + 1;
            const float* xr = xg + (4 * php - 1 + lr) * 250;
            const float2 e0 = ld2(xr + c1);
            const float2 e1 = ld2(xr + 4 * pw);
            const float2 e2 = ld2(xr + c3);
            xw[lr*6+0] = lok ? e0.x : 0.f;  xw[lr*6+1] = lok ? e0.y : 0.f;
            xw[lr*6+2] = e1.x;              xw[lr*6+3] = e1.y;
            xw[lr*6+4] = rok ? e2.x : 0.f;  xw[lr*6+5] = rok ? e2.y : 0.f;
        });
        {   // lr = 5 : input row 4php+4, OOB only when php==7
            const bool ok = (php < 7);
            const float* xr = xg + (ok ? (4 * php + 4) : 31) * 250;
            const float2 e0 = ld2(xr + c1);
            const float2 e1 = ld2(xr + 4 * pw);
            const float2 e2 = ld2(xr + c3);
            const bool okl = ok & lok, okr = ok & rok;
            xw[30] = okl ? e0.x : 0.f;  xw[31] = okl ? e0.y : 0.f;
            xw[32] = ok  ? e1.x : 0.f;  xw[33] = ok  ? e1.y : 0.f;
            xw[34] = okr ? e2.x : 0.f;  xw[35] = okr ? e2.y : 0.f;
        }
    };

    ldx(xwA, php0, pw0);     // issue all 36+36 global loads first ...
    ldx(xwB, php1, pw1);

    // ---- LDS pad init (zero row + col pads) runs while the loads are in flight ----
    if (t < 68) ZR[t] = 0.f;
    for (int i = t; i < 640; i += 256) {          // h1p cols 0 and 64..67
        const int ch = i / 80, j = i - ch * 80;
        const int r = j / 5, k = j - r * 5;
        A[ch * 1088 + r * 68 + ((k == 0) ? 0 : (63 + k))] = 0.f;
    }
    for (int i = t; i < 128; i += 256) {          // h2p col pads 0 and 17
        const int ch = i >> 3, r = (i >> 1) & 3;
        H2[ch * 80 + r * 20 + ((i & 1) ? 17 : 0)] = 0.f;
    }

    auto cmp1 = [&](const float (&xw)[36], const int php, const int pw,
                    const bool dostore) AIL {
        const int sb = (2 * php) * 68 + pw + 1;          // col c -> idx c+1
        static_for<8>([&](auto OC) AIL {
            constexpr int oc = OC.value;
            const float4 q0 = ld4(w1l + oc * 12);        // uniform -> SGPR
            const float4 q1 = ld4(w1l + oc * 12 + 4);
            const float4 q2 = ld4(w1l + oc * 12 + 8);
            float p[8];                                   // [conv_row j][dc]
            static_for<8>([&](auto I) AIL { p[I.value] = 0.f; });
            static_for<3>([&](auto KH) AIL {
                constexpr int kh = KH.value;
                static_for<4>([&](auto KW) AIL {
                    constexpr int kw = KW.value;
                    const float wv = w12<kh * 4 + kw>(q0, q1, q2);
                    static_for<4>([&](auto J) AIL {       // conv rows 4php+j
                        constexpr int j = J.value;
                        p[j*2+0] = fmaf(wv, xw[(j + kh) * 6 + kw],     p[j*2+0]);
                        p[j*2+1] = fmaf(wv, xw[(j + kh) * 6 + kw + 2], p[j*2+1]);
                    });
                });
            });
            // pool rows {j=0,1} -> out row 2php ; {j=2,3} -> out row 2php+1
            const float m0 = fmaxf(fmaxf(p[0], p[1]), fmaxf(p[2], p[3]));
            const float m1 = fmaxf(fmaxf(p[4], p[5]), fmaxf(p[6], p[7]));
            const float v0 = fmaxf(m0 + b1l[oc], 0.f);
            const float v1 = fmaxf(m1 + b1l[oc], 0.f);
            if (dostore) {
                A[oc * 1088 + sb]      = v0;
                A[oc * 1088 + sb + 68] = v1;
            }
        });
    };
    cmp1(xwA, php0, pw0, true);
    cmp1(xwB, php1, pw1, valid1);
    __syncthreads();

    // ===== conv2 (16,8,4,3) s(2,2) p(1,1) + pool2 + relu -> h2p (16,4,16) ==========
    // 2-deep software pipeline over ic: prefetch ic+1's 12 LDS reads while
    // computing ic (named double buffers, all indices compile-time). All 12
    // uniform weight float4s of an ic-step are issued together at the top of
    // cmpic so one s_load latency covers all 4 ol FMA bursts.
    {
        const int s2 = t & 63;
        const int ogu = __builtin_amdgcn_readfirstlane(t >> 6);   // wave-uniform
        const int ph2 = s2 >> 4, pw2 = s2 & 15;
        struct Buf2 { float4 ya[6]; float2 yb[6]; };
        Buf2 bA, bB;
        const float* const Pz = ZR + 4 * pw2;
        const float* const Pm = A + (4 * ph2 - 1) * 68 + 4 * pw2; // row r: +r*68+ic*1088

        auto ldic = [&](auto ICC, Buf2& bb) AIL {
            constexpr int ic = ICC.value;
            {   // r=0: OOB only when ph2==0 -> zero row
                const float* hp = (ph2 > 0) ? (Pm + ic * 1088) : Pz;
                bb.ya[0] = ld4(hp); bb.yb[0] = ld2(hp + 4);
            }
            static_for<4>([&](auto RR) AIL {   // r=1..4 always in-range -> imm offsets
                constexpr int r = RR.value + 1;
                const float* hp = Pm + ic * 1088 + r * 68;
                bb.ya[r] = ld4(hp); bb.yb[r] = ld2(hp + 4);
            });
            {   // r=5: OOB only when ph2==3 -> zero row
                const float* hp = (ph2 < 3) ? (Pm + ic * 1088 + 5 * 68) : Pz;
                bb.ya[5] = ld4(hp); bb.yb[5] = ld2(hp + 4);
            }
        };

        float a2[16];
        static_for<16>([&](auto I) AIL { a2[I.value] = 0.f; });

        auto cmpic = [&](auto ICC, const Buf2& bb) AIL {
            constexpr int ic = ICC.value;
            const float* wpb = w2g + ((size_t)((l * 16 + ogu * 4) * 8 + ic)) * 12;
            float4 q[4][3];                                 // uniform -> SGPR quads
            static_for<4>([&](auto OL) AIL {
                constexpr int ol = OL.value;
                const float* wp = wpb + (size_t)ol * 96;    // ((..+ol)*8+ic)*12
                q[ol][0] = ld4(wp); q[ol][1] = ld4(wp + 4); q[ol][2] = ld4(wp + 8);
            });
            static_for<4>([&](auto OL) AIL {
                constexpr int ol = OL.value;
                static_for<4>([&](auto KH) AIL {
                    constexpr int kh = KH.value;
                    static_for<3>([&](auto KW) AIL {
                        constexpr int kw = KW.value;
                        const float wv = w12<kh * 3 + kw>(q[ol][0], q[ol][1], q[ol][2]);
                        a2[ol*4+0] = fmaf(wv, f6<kw>(bb.ya[kh], bb.yb[kh]), a2[ol*4+0]);
                        a2[ol*4+1] = fmaf(wv, f6<kw + 2>(bb.ya[kh], bb.yb[kh]), a2[ol*4+1]);
                        a2[ol*4+2] = fmaf(wv, f6<kw>(bb.ya[kh + 2], bb.yb[kh + 2]), a2[ol*4+2]);
                        a2[ol*4+3] = fmaf(wv, f6<kw + 2>(bb.ya[kh + 2], bb.yb[kh + 2]), a2[ol*4+3]);
                    });
                });
            });
        };

        ldic(std::integral_constant<int, 0>{}, bA);
        static_for<8>([&](auto IC) AIL {
            constexpr int ic = IC.value;
            if constexpr (ic < 7) {
                if constexpr ((ic + 1) & 1) ldic(std::integral_constant<int, ic + 1>{}, bB);
                else                        ldic(std::integral_constant<int, ic + 1>{}, bA);
            }
            if constexpr (ic & 1) cmpic(IC, bB);
            else                  cmpic(IC, bA);
        });

        static_for<4>([&](auto OL) AIL {
            constexpr int ol = OL.value;
            const int oc = ogu * 4 + ol;
            const float m = fmaxf(fmaxf(a2[ol*4+0], a2[ol*4+1]),
                                  fmaxf(a2[ol*4+2], a2[ol*4+3]));
            H2[oc * 80 + ph2 * 20 + pw2 + 1] = fmaxf(m + b2g[l * 16 + oc], 0.f);
        });
    }
    __syncthreads();

    // ===== conv3 (32,16,3,4) s(1,2) p(1,1) + pool2 + relu -> sh3 (32,2,4) ==========
    // Same 2-deep pipeline; also prefetches the per-lane global weight loads.
    {
        const int oc3 = t >> 3, s3 = t & 7;
        const int ph3 = s3 >> 2, pw3 = s3 & 3;
        const float* w3l = w3g + (size_t)l * 6144 + oc3 * 192;
        const float b3v = b3g[l * 32 + oc3];
        struct Buf3 { float4 za[4]; float2 zb[4]; float4 q0, q1, q2; };
        Buf3 cA, cB;
        const float* const Pz = ZR + 4 * pw3;
        const float* const Pm = H2 + (2 * ph3 - 1) * 20 + 4 * pw3; // row r: +r*20+ic*80

        auto ldic3 = [&](auto ICC, Buf3& bb) AIL {
            constexpr int ic = ICC.value;
            {   // r=0: OOB only when ph3==0
                const float* zp = (ph3 > 0) ? (Pm + ic * 80) : Pz;
                bb.za[0] = ld4(zp); bb.zb[0] = ld2(zp + 4);
            }
            static_for<2>([&](auto RR) AIL {   // r=1,2 always in-range
                constexpr int r = RR.value + 1;
                const float* zp = Pm + ic * 80 + r * 20;
                bb.za[r] = ld4(zp); bb.zb[r] = ld2(zp + 4);
            });
            {   // r=3: OOB only when ph3==1
                const float* zp = (ph3 < 1) ? (Pm + ic * 80 + 3 * 20) : Pz;
                bb.za[3] = ld4(zp); bb.zb[3] = ld2(zp + 4);
            }
            bb.q0 = ld4(w3l + ic * 12);
            bb.q1 = ld4(w3l + ic * 12 + 4);
            bb.q2 = ld4(w3l + ic * 12 + 8);
        };

        float a30 = 0.f, a31 = 0.f, a32 = 0.f, a33 = 0.f;
        auto cmpic3 = [&](const Buf3& bb) AIL {
            static_for<3>([&](auto KH) AIL {
                constexpr int kh = KH.value;
                static_for<4>([&](auto KW) AIL {
                    constexpr int kw = KW.value;
                    const float wv = w12<kh * 4 + kw>(bb.q0, bb.q1, bb.q2);
                    a30 = fmaf(wv, f6<kw>(bb.za[kh], bb.zb[kh]), a30);
                    a31 = fmaf(wv, f6<kw + 2>(bb.za[kh], bb.zb[kh]), a31);
                    a32 = fmaf(wv, f6<kw>(bb.za[kh + 1], bb.zb[kh + 1]), a32);
                    a33 = fmaf(wv, f6<kw + 2>(bb.za[kh + 1], bb.zb[kh + 1]), a33);
                });
            });
        };

        ldic3(std::integral_constant<int, 0>{}, cA);
        static_for<16>([&](auto IC) AIL {
            constexpr int ic = IC.value;
            if constexpr (ic < 15) {
                if constexpr ((ic + 1) & 1) ldic3(std::integral_constant<int, ic + 1>{}, cB);
                else                        ldic3(std::integral_constant<int, ic + 1>{}, cA);
            }
            if constexpr (ic & 1) cmpic3(cB);
            else                  cmpic3(cA);
        });

        const float m = fmaxf(fmaxf(a30, a31), fmaxf(a32, a33));
        A[oc3 * 8 + s3] = fmaxf(m + b3v, 0.f);    // sh3, h1p region is dead
    }
    __syncthreads();

    // ===== conv4 (64,32,2,4) VALID -> (64,) + fc-weight staging ====================
    {
        if (t < 192) A[600 + t] = fcwg[l * 192 + t];
        else if (t < 195) A[600 + t] = fcbg[l * 3 + (t - 192)];

        const int oc4 = t >> 2, part = t & 3;
        const float* w4p = w4g + (size_t)l * 16384 + oc4 * 256 + part * 64;
        float s4 = 0.f;
        static_for<8>([&](auto J) AIL {
            constexpr int j = J.value;
            const float4 wa = ld4(w4p + j * 8);
            const float4 wb = ld4(w4p + j * 8 + 4);
            const float* xx = A + (part * 8 + j) * 8;
            const float4 xA = ld4(xx), xB = ld4(xx + 4);
            s4 = fmaf(wa.x, xA.x, s4); s4 = fmaf(wa.y, xA.y, s4);
            s4 = fmaf(wa.z, xA.z, s4); s4 = fmaf(wa.w, xA.w, s4);
            s4 = fmaf(wb.x, xB.x, s4); s4 = fmaf(wb.y, xB.y, s4);
            s4 = fmaf(wb.z, xB.z, s4); s4 = fmaf(wb.w, xB.w, s4);
        });
        A[256 + part * 64 + oc4] = s4;            // spart
    }
    __syncthreads();
    if (t < 64)
        A[512 + t] = A[256 + t] + A[320 + t] + A[384 + t] + A[448 + t]
                   + b4g[l * 64 + t];             // shf
    __syncthreads();

    // ===== FC (3x64) + softmax =====================================================
    if (t < 3) {
        float s = A[792 + t];                     // fcb
        static_for<64>([&](auto I) AIL {
            s = fmaf(A[600 + t * 64 + I.value], A[512 + I.value], s);
        });
        A[580 + t] = s;                           // slog
    }
    __syncthreads();
    if (t == 0) {
        const float a0 = A[580], a1 = A[581], a2 = A[582];
        const float m = fmaxf(a0, fmaxf(a1, a2));
        const float e0 = expf(a0 - m), e1 = expf(a1 - m), e2 = expf(a2 - m);
        const float inv = 1.f / (e0 + e1 + e2);
        float* pr = preds + ((size_t)b * NLEADS + l) * 3;
        pr[0] = e0 * inv; pr[1] = e1 * inv; pr[2] = e2 * inv;
    }
}

// Cross-lead multiplicative fusion loss. One thread per (b, class).
__global__ void fusion_loss_kernel(const float* __restrict__ preds,
                                   float* __restrict__ out, int B)
{
    const int idx = blockIdx.x * blockDim.x + threadIdx.x;
    if (idx >= B * 3) return;
    const int b = idx / 3;
    const int c = idx - 3 * b;
    const float* p = preds + (size_t)b * (NLEADS * 3) + c;
    float S = 0.f;                                // log prod(1-pj)
    for (int j = 0; j < NLEADS; ++j) S += logf(1.f - p[j * 3]);
    const float be = 2.0f / 60.0f;
    float loss = 0.f;
    for (int j = 0; j < NLEADS; ++j) {
        const float pj = p[j * 3];
        loss += expf(be * (S - logf(1.f - pj))) * logf(pj);
    }
    out[idx] = -loss;
}

extern "C" void kernel_launch(void* const* d_in, const int* in_sizes, int n_in,
                              void* d_out, int out_size, void* d_ws, size_t ws_size,
                              hipStream_t stream)
{
    const float* x   = (const float*)d_in[0];
    const float* w1  = (const float*)d_in[1];
    const float* b1  = (const float*)d_in[2];
    const float* w2  = (const float*)d_in[3];
    const float* b2  = (const float*)d_in[4];
    const float* w3  = (const float*)d_in[5];
    const float* b3  = (const float*)d_in[6];
    const float* w4  = (const float*)d_in[7];
    const float* b4  = (const float*)d_in[8];
    const float* fcw = (const float*)d_in[9];
    const float* fcb = (const float*)d_in[10];

    const int B = in_sizes[0] / (NLEADS * 32 * 250);   // 128
    float* preds = (float*)d_ws;                        // B*61*3 floats

    dim3 grid(B, NLEADS);
    hipLaunchKernelGGL(lead_cnn_kernel, grid, dim3(256), 0, stream,
                       x, w1, b1, w2, b2, w3, b3, w4, b4, fcw, fcb, preds);

    const int total = B * 3;
    hipLaunchKernelGGL(fusion_loss_kernel, dim3((total + 255) / 256), dim3(256),
                       0, stream, preds, (float*)d_out, B);
}